// Round 7
// baseline (626.287 us; speedup 1.0000x reference)
//
#include <hip/hip_runtime.h>
#include <hip/hip_bf16.h>
#include <cstdint>

#define DIM   768
#define HEADS 12
#define HD    64
#define NTOK  197
#define BATCH 64
#define MROWS (BATCH*NTOK)   /* 12608 */
#define MPAD  12672          /* 99*128 */
#define HIDN  3072
#define QSCALE 0.125f
#define LNEPS 1e-6f

typedef __bf16 bf16;
typedef __bf16 bf16x8 __attribute__((ext_vector_type(8)));
typedef __bf16 bf16x4 __attribute__((ext_vector_type(4)));
typedef float  f32x4  __attribute__((ext_vector_type(4)));

__device__ inline void gload_lds16(const void* src, void* dst) {
  __builtin_amdgcn_global_load_lds(
      (__attribute__((address_space(1))) void*)(src),
      (__attribute__((address_space(3))) void*)(dst), 16, 0, 0);
}

#define WAIT_LGKM0() do { asm volatile("s_waitcnt lgkmcnt(0)" ::: "memory"); \
                          __builtin_amdgcn_sched_barrier(0); } while (0)

// ---------------- weight f32 -> bf16 convert ----------------
__global__ __launch_bounds__(256) void conv_kernel(const float* __restrict__ in,
                                                   bf16* __restrict__ out, int n4) {
  int i = blockIdx.x * 256 + threadIdx.x;
  if (i < n4) {
    float4 f = ((const float4*)in)[i];
    bf16x4 o; o.x = (bf16)f.x; o.y = (bf16)f.y; o.z = (bf16)f.z; o.w = (bf16)f.w;
    ((bf16x4*)out)[i] = o;
  }
}

// ---------------- relative position bias precompute ----------------
__global__ __launch_bounds__(256) void bias_kernel(const float* __restrict__ rh,
                                                   const float* __restrict__ rw,
                                                   const int* __restrict__ hidx,
                                                   const int* __restrict__ widx,
                                                   float* __restrict__ bias) {
  int idx = blockIdx.x * 256 + threadIdx.x;
  const int NN = NTOK * NTOK;
  if (idx >= HEADS * NN) return;
  int h  = idx / NN;
  int ij = idx - h * NN;
  bias[idx] = rh[hidx[ij] * HEADS + h] + rw[widx[ij] * HEADS + h];
}

// ---------------- LayerNorm f32 -> bf16 ----------------
__global__ __launch_bounds__(256) void ln_kernel(const float* __restrict__ x,
                                                 const float* __restrict__ w,
                                                 const float* __restrict__ b,
                                                 bf16* __restrict__ out) {
  int row = blockIdx.x;
  int tid = threadIdx.x;
  const float* xr = x + (size_t)row * DIM;
  float v0 = xr[tid], v1 = xr[tid + 256], v2 = xr[tid + 512];
  float s  = v0 + v1 + v2;
  float s2 = v0 * v0 + v1 * v1 + v2 * v2;
#pragma unroll
  for (int d = 1; d < 64; d <<= 1) { s += __shfl_xor(s, d); s2 += __shfl_xor(s2, d); }
  __shared__ float red[8];
  int wv = tid >> 6, ln = tid & 63;
  if (ln == 0) { red[wv] = s; red[wv + 4] = s2; }
  __syncthreads();
  s  = red[0] + red[1] + red[2] + red[3];
  s2 = red[4] + red[5] + red[6] + red[7];
  float mean = s * (1.0f / DIM);
  float var  = s2 * (1.0f / DIM) - mean * mean;
  float rs   = rsqrtf(var + LNEPS);
  bf16* outr = out + (size_t)row * DIM;
  outr[tid]       = (bf16)((v0 - mean) * rs * w[tid]       + b[tid]);
  outr[tid + 256] = (bf16)((v1 - mean) * rs * w[tid + 256] + b[tid + 256]);
  outr[tid + 512] = (bf16)((v2 - mean) * rs * w[tid + 512] + b[tid + 512]);
}

// ---------------- 128x128 BK=64 swizzled 2-phase GEMM: C = A[M,K] * Bw[N,K]^T ----
// grid = (Mtiles, Ntiles): consecutive blocks read distinct A panels, share B.
// EPI 0: qkv scatter; 1: residual f32; 2: gelu bf16.
template <int EPI>
__global__ __launch_bounds__(256, 2)
void gemm128(const bf16* __restrict__ A, const bf16* __restrict__ Bw,
             int K, int Ncols,
             const float* __restrict__ p0, const float* __restrict__ p1,
             void* __restrict__ outp) {
  __shared__ __align__(16) bf16 As[2][128 * 64];   // 2x16KB
  __shared__ __align__(16) bf16 Bs[2][128 * 64];   // 2x16KB
  const int tid  = threadIdx.x;
  const int wave = tid >> 6, lane = tid & 63;
  const int wm = wave >> 1, wn = wave & 1;       // 2x2 wave grid, 64x64 out per wave
  const int lr16 = lane & 15, hi16 = lane >> 4;
  const int rowBase = blockIdx.x * 128;          // M tile (fast-varying)
  const int colBase = blockIdx.y * 128;          // N tile
  const size_t Kb = (size_t)K * 2;
  const int KT = K >> 6;

  // swizzle: LDS[row][unit u] = G[row][u ^ (row&7)]; read unit g -> u = g ^ (row&7)
  const int s7 = lr16 & 7;
  const int colk0 = (hi16 ^ s7) * 16;          // kk=0 (k 0..31)
  const int colk1 = ((4 + hi16) ^ s7) * 16;    // kk=1 (k 32..63)
  const int rowb_a = (wm * 64 + lr16) * 128;   // + m*2048
  const int rowb_b = (wn * 64 + lr16) * 128;   // + n*2048

  // staging: round r covers rows r*32 + wave*8 + (lane>>3); lane unit = lane&7
  const int srow = wave * 8 + (lane >> 3);
  const int scb  = (((lane & 7) ^ ((lane >> 3) & 7)) * 16);
  const char* aSrcP[4];
  const char* bSrcP[4];
#pragma unroll
  for (int r = 0; r < 4; ++r) {
    int ra = rowBase + r * 32 + srow;
    if (ra > MROWS - 1) ra = MROWS - 1;        // clamp A rows (tail tile)
    aSrcP[r] = (const char*)A + (size_t)ra * Kb + scb;
    bSrcP[r] = (const char*)Bw + (size_t)(colBase + r * 32 + srow) * Kb + scb;
  }

  f32x4 acc[4][4] = {};

  auto stage = [&](int t, int buf) {
    const size_t koff = (size_t)t * 128;
#pragma unroll
    for (int r = 0; r < 4; ++r)
      gload_lds16(aSrcP[r] + koff, (char*)&As[buf][0] + (r * 32 + wave * 8) * 128);
#pragma unroll
    for (int r = 0; r < 4; ++r)
      gload_lds16(bSrcP[r] + koff, (char*)&Bs[buf][0] + (r * 32 + wave * 8) * 128);
  };

  auto compute = [&](int buf) {
    const char* Ab = (const char*)&As[buf][0];
    const char* Bb = (const char*)&Bs[buf][0];
    bf16x8 bfr[4][2], afr[4][2];
#pragma unroll
    for (int n = 0; n < 4; ++n) {
      bfr[n][0] = *(const bf16x8*)(Bb + rowb_b + n * 2048 + colk0);
      bfr[n][1] = *(const bf16x8*)(Bb + rowb_b + n * 2048 + colk1);
    }
#pragma unroll
    for (int m = 0; m < 4; ++m) {
      afr[m][0] = *(const bf16x8*)(Ab + rowb_a + m * 2048 + colk0);
      afr[m][1] = *(const bf16x8*)(Ab + rowb_a + m * 2048 + colk1);
    }
    WAIT_LGKM0();
    __builtin_amdgcn_s_setprio(1);
#pragma unroll
    for (int m = 0; m < 4; ++m)
#pragma unroll
      for (int n = 0; n < 4; ++n) {
        acc[m][n] = __builtin_amdgcn_mfma_f32_16x16x32_bf16(afr[m][0], bfr[n][0], acc[m][n], 0, 0, 0);
        acc[m][n] = __builtin_amdgcn_mfma_f32_16x16x32_bf16(afr[m][1], bfr[n][1], acc[m][n], 0, 0, 0);
      }
    __builtin_amdgcn_s_setprio(0);
  };

  // 2-phase pipeline: stage(t+1) issued before compute(t); one barrier per tile.
  stage(0, 0);
  __syncthreads();              // vmcnt(0)+lgkmcnt(0)+barrier: tile 0 visible
  int cur = 0;
  for (int t = 0; t < KT - 1; ++t) {
    stage(t + 1, cur ^ 1);      // overlaps with compute below
    compute(cur);
    __syncthreads();            // drains vmcnt (stage t+1 landed); all reads of cur done
    cur ^= 1;
  }
  compute(cur);                 // last tile, no prefetch

  // ---- epilogue (C/D layout: col=lane&15, row=(lane>>4)*4+reg)
  const int rl = hi16 * 4;
  const int cl = lr16;
#pragma unroll
  for (int m = 0; m < 4; ++m) {
#pragma unroll
    for (int n = 0; n < 4; ++n) {
#pragma unroll
      for (int r = 0; r < 4; ++r) {
        int row = rowBase + wm * 64 + m * 16 + rl + r;
        int col = colBase + wn * 64 + n * 16 + cl;
        if (row >= MROWS) continue;
        float v = acc[m][n][r];
        if constexpr (EPI == 0) {
          int which = col / DIM;
          int jj = col - which * DIM;
          if (which == 0) v = (v + p0[jj]) * QSCALE;
          else if (which == 2) v = v + p1[jj];
          int bb = row / NTOK, nt = row - bb * NTOK;
          int h = jj >> 6, hd = jj & 63;
          ((bf16*)outp)[((size_t)(which * 768 + bb * HEADS + h) * NTOK + nt) * 64 + hd] = (bf16)v;
        } else if constexpr (EPI == 1) {
          ((float*)outp)[(size_t)row * Ncols + col] =
              p1[(size_t)row * Ncols + col] + v + p0[col];
        } else {
          float t2 = v + p0[col];
          float g = 0.5f * t2 * (1.0f + erff(t2 * 0.70710678118654752f));
          ((bf16*)outp)[(size_t)row * Ncols + col] = (bf16)g;
        }
      }
    }
  }
}

// ---------------- fused attention v3: flash-style online softmax ----------------
#define VTS 232   /* Vt row stride (elements) */
__global__ __launch_bounds__(256, 4)
void attn_kernel(const bf16* __restrict__ qkv, const float* __restrict__ bias,
                 bf16* __restrict__ out) {
  const int bh = blockIdx.x;
  const int b = bh / HEADS, h = bh - b * HEADS;
  const bf16* qg = qkv + (size_t)bh * NTOK * HD;
  const bf16* kg = qg + (size_t)768 * NTOK * HD;
  const bf16* vg = qg + (size_t)1536 * NTOK * HD;

  __shared__ __align__(16) bf16 Vt[64 * VTS];       // 29.0KB
  __shared__ __align__(16) bf16 Ps[4][2][16 * 40];  // 10.0KB dbuf P chunks

  const int tid = threadIdx.x;
  for (int i = tid; i < NTOK * HD; i += 256) {
    int j = i >> 6, d = i & 63;
    Vt[d * VTS + j] = vg[i];
  }
  for (int i = tid; i < 64 * (VTS - NTOK); i += 256) {
    int d = i / (VTS - NTOK), j = NTOK + (i - d * (VTS - NTOK));
    Vt[d * VTS + j] = (bf16)0.0f;
  }
  __syncthreads();

  const int wave = tid >> 6, lane = tid & 63;
  const int lr = lane & 15, lg = lane >> 4;
  const int tstart = (wave == 0) ? 0 : 1 + wave * 3;   // 0,4,7,10
  const int tcount = (wave == 0) ? 4 : 3;
  const float* bh_bias = bias + (size_t)h * NTOK * NTOK;

  for (int ti = 0; ti < tcount; ++ti) {
    const int mi = tstart + ti;
    int qrow = mi * 16 + lr; if (qrow > NTOK - 1) qrow = NTOK - 1;
    bf16x8 aq0 = *(const bf16x8*)(qg + (size_t)qrow * 64 + lg * 8);
    bf16x8 aq1 = *(const bf16x8*)(qg + (size_t)qrow * 64 + 32 + lg * 8);

    f32x4 oacc[4] = {};
    float m[4] = {-1e30f, -1e30f, -1e30f, -1e30f};
    float l[4] = {0.f, 0.f, 0.f, 0.f};
    const int ivb = (mi * 16 + lg * 4 < NTOK) ? mi * 16 + lg * 4 : NTOK - 1;

#pragma unroll 1
    for (int kt = 0; kt < 7; ++kt) {
      const int j0 = kt * 32 + lr;
      const bf16* kp0 = kg + (size_t)(kt * 32 + lr) * 64 + lg * 8;
      const bf16* kp1 = kp0 + (size_t)16 * 64;
      f32x4 s0 = {}, s1 = {};
      s0 = __builtin_amdgcn_mfma_f32_16x16x32_bf16(aq0, *(const bf16x8*)kp0, s0, 0, 0, 0);
      s0 = __builtin_amdgcn_mfma_f32_16x16x32_bf16(aq1, *(const bf16x8*)(kp0 + 32), s0, 0, 0, 0);
      s1 = __builtin_amdgcn_mfma_f32_16x16x32_bf16(aq0, *(const bf16x8*)kp1, s1, 0, 0, 0);
      s1 = __builtin_amdgcn_mfma_f32_16x16x32_bf16(aq1, *(const bf16x8*)(kp1 + 32), s1, 0, 0, 0);

      bf16* buf = &Ps[wave][kt & 1][0];
#pragma unroll
      for (int r = 0; r < 4; ++r) {
        int iv = ivb + r; if (iv > NTOK - 1) iv = NTOK - 1;
        float sv0 = (j0 < NTOK)      ? s0[r] + bh_bias[(size_t)iv * NTOK + j0]      : -1e30f;
        float sv1 = (j0 + 16 < NTOK) ? s1[r] + bh_bias[(size_t)iv * NTOK + j0 + 16] : -1e30f;
        float cmax = fmaxf(sv0, sv1);
#pragma unroll
        for (int d = 1; d < 16; d <<= 1) cmax = fmaxf(cmax, __shfl_xor(cmax, d));
        float mnew = fmaxf(m[r], cmax);
        float scale = __expf(m[r] - mnew);
        m[r] = mnew;
        float e0 = __expf(sv0 - mnew);
        float e1 = __expf(sv1 - mnew);
        l[r] = l[r] * scale + e0 + e1;
#pragma unroll
        for (int nd = 0; nd < 4; ++nd) oacc[nd][r] *= scale;
        buf[(lg * 4 + r) * 40 + lr]      = (bf16)e0;
        buf[(lg * 4 + r) * 40 + 16 + lr] = (bf16)e1;
      }
      asm volatile("s_waitcnt lgkmcnt(0)" ::: "memory");
      __builtin_amdgcn_sched_barrier(0);
      bf16x8 pa = *(const bf16x8*)&buf[lr * 40 + lg * 8];
#pragma unroll
      for (int nd = 0; nd < 4; ++nd) {
        bf16x8 bv = *(const bf16x8*)&Vt[(nd * 16 + lr) * VTS + kt * 32 + lg * 8];
        oacc[nd] = __builtin_amdgcn_mfma_f32_16x16x32_bf16(pa, bv, oacc[nd], 0, 0, 0);
      }
    }

    float rowinv[4];
#pragma unroll
    for (int r = 0; r < 4; ++r) {
      float ls = l[r];
#pragma unroll
      for (int d = 1; d < 16; d <<= 1) ls += __shfl_xor(ls, d);
      rowinv[r] = 1.0f / ls;
    }

    bf16* Ob = &Ps[wave][0][0];
#pragma unroll
    for (int nd = 0; nd < 4; ++nd)
#pragma unroll
      for (int r = 0; r < 4; ++r)
        Ob[(lg * 4 + r) * 72 + nd * 16 + lr] = (bf16)(oacc[nd][r] * rowinv[r]);
    asm volatile("s_waitcnt lgkmcnt(0)" ::: "memory");
    __builtin_amdgcn_sched_barrier(0);
    const int rows = NTOK - mi * 16;
#pragma unroll
    for (int pass = 0; pass < 2; ++pass) {
      int orow = pass * 8 + (lane >> 3);
      if (orow < rows) {
        bf16x8 v = *(const bf16x8*)&Ob[orow * 72 + (lane & 7) * 8];
        *(bf16x8*)(out + (size_t)(b * NTOK + mi * 16 + orow) * DIM + h * 64 + (lane & 7) * 8) = v;
      }
    }
  }
}

// ---------------- launch ----------------
extern "C" void kernel_launch(void* const* d_in, const int* in_sizes, int n_in,
                              void* d_out, int out_size, void* d_ws, size_t ws_size,
                              hipStream_t stream) {
  const float* x    = (const float*)d_in[0];
  const float* n1w  = (const float*)d_in[1];
  const float* n1b  = (const float*)d_in[2];
  const float* qkvw = (const float*)d_in[3];
  const float* qb   = (const float*)d_in[4];
  const float* vb   = (const float*)d_in[5];
  const float* pw   = (const float*)d_in[6];
  const float* pb   = (const float*)d_in[7];
  const float* rh   = (const float*)d_in[8];
  const float* rw   = (const float*)d_in[9];
  const float* n2w  = (const float*)d_in[10];
  const float* n2b  = (const float*)d_in[11];
  const float* f1w  = (const float*)d_in[12];
  const float* f1b  = (const float*)d_in[13];
  const float* f2w  = (const float*)d_in[14];
  const float* f2b  = (const float*)d_in[15];
  const int* hidx   = (const int*)d_in[16];
  const int* widx   = (const int*)d_in[17];

  char* ws = (char*)d_ws;
  size_t off = 0;
  auto alloc = [&](size_t bytes) {
    void* p = ws + off;
    off += (bytes + 255) & ~(size_t)255;
    return p;
  };
  bf16* wqkv  = (bf16*)alloc((size_t)2304 * 768 * 2);
  bf16* wproj = (bf16*)alloc((size_t)768 * 768 * 2);
  bf16* wfc1  = (bf16*)alloc((size_t)3072 * 768 * 2);
  bf16* wfc2  = (bf16*)alloc((size_t)768 * 3072 * 2);
  float* biasT = (float*)alloc((size_t)HEADS * NTOK * NTOK * 4);
  bf16* hbf = (bf16*)alloc((size_t)MROWS * 768 * 2);
  float* x1 = (float*)alloc((size_t)MROWS * 768 * 4);
  char* region = (char*)alloc((size_t)MPAD * HIDN * 2);
  bf16* qkv   = (bf16*)region;                                       // 58.1 MB
  bf16* attno = (bf16*)(region + (size_t)2304 * NTOK * 64 * 2);      // 19.4 MB
  bf16* mbuf  = (bf16*)region;                                       // FC1 out overlays qkv+attno

  conv_kernel<<<(2304 * 768 / 4 + 255) / 256, 256, 0, stream>>>(qkvw, wqkv, 2304 * 768 / 4);
  conv_kernel<<<(768 * 768 / 4 + 255) / 256, 256, 0, stream>>>(pw, wproj, 768 * 768 / 4);
  conv_kernel<<<(3072 * 768 / 4 + 255) / 256, 256, 0, stream>>>(f1w, wfc1, 3072 * 768 / 4);
  conv_kernel<<<(768 * 3072 / 4 + 255) / 256, 256, 0, stream>>>(f2w, wfc2, 768 * 3072 / 4);
  bias_kernel<<<(HEADS * NTOK * NTOK + 255) / 256, 256, 0, stream>>>(rh, rw, hidx, widx, biasT);

  ln_kernel<<<MROWS, 256, 0, stream>>>(x, n1w, n1b, hbf);
  gemm128<0><<<dim3(MPAD / 128, 2304 / 128), 256, 0, stream>>>(hbf, wqkv, 768, 2304, qb, vb, qkv);
  attn_kernel<<<768, 256, 0, stream>>>(qkv, biasT, attno);
  gemm128<1><<<dim3(MPAD / 128, 768 / 128), 256, 0, stream>>>(attno, wproj, 768, 768, pb, x, x1);
  ln_kernel<<<MROWS, 256, 0, stream>>>(x1, n2w, n2b, hbf);
  gemm128<2><<<dim3(MPAD / 128, HIDN / 128), 256, 0, stream>>>(hbf, wfc1, 768, HIDN, f1b, nullptr, mbuf);
  gemm128<1><<<dim3(MPAD / 128, 768 / 128), 256, 0, stream>>>(mbuf, wfc2, HIDN, 768, f2b, x1, d_out);
}

// Round 8
// 433.791 us; speedup vs baseline: 1.4438x; 1.4438x over previous
//
#include <hip/hip_runtime.h>
#include <hip/hip_bf16.h>
#include <cstdint>

#define DIM   768
#define HEADS 12
#define HD    64
#define NTOK  197
#define BATCH 64
#define MROWS (BATCH*NTOK)   /* 12608 */
#define MPAD  12672          /* 99*128 */
#define HIDN  3072
#define QSCALE 0.125f
#define LNEPS 1e-6f

typedef __bf16 bf16;
typedef __bf16 bf16x8 __attribute__((ext_vector_type(8)));
typedef __bf16 bf16x4 __attribute__((ext_vector_type(4)));
typedef float  f32x4  __attribute__((ext_vector_type(4)));

__device__ inline void gload_lds16(const void* src, void* dst) {
  __builtin_amdgcn_global_load_lds(
      (__attribute__((address_space(1))) void*)(src),
      (__attribute__((address_space(3))) void*)(dst), 16, 0, 0);
}

// ---------------- weight f32 -> bf16 convert ----------------
__global__ __launch_bounds__(256) void conv_kernel(const float* __restrict__ in,
                                                   bf16* __restrict__ out, int n4) {
  int i = blockIdx.x * 256 + threadIdx.x;
  if (i < n4) {
    float4 f = ((const float4*)in)[i];
    bf16x4 o; o.x = (bf16)f.x; o.y = (bf16)f.y; o.z = (bf16)f.z; o.w = (bf16)f.w;
    ((bf16x4*)out)[i] = o;
  }
}

// ---------------- relative position bias precompute ----------------
__global__ __launch_bounds__(256) void bias_kernel(const float* __restrict__ rh,
                                                   const float* __restrict__ rw,
                                                   const int* __restrict__ hidx,
                                                   const int* __restrict__ widx,
                                                   float* __restrict__ bias) {
  int idx = blockIdx.x * 256 + threadIdx.x;
  const int NN = NTOK * NTOK;
  if (idx >= HEADS * NN) return;
  int h  = idx / NN;
  int ij = idx - h * NN;
  bias[idx] = rh[hidx[ij] * HEADS + h] + rw[widx[ij] * HEADS + h];
}

// ---------------- LayerNorm f32 -> bf16 ----------------
__global__ __launch_bounds__(256) void ln_kernel(const float* __restrict__ x,
                                                 const float* __restrict__ w,
                                                 const float* __restrict__ b,
                                                 bf16* __restrict__ out) {
  int row = blockIdx.x;
  int tid = threadIdx.x;
  const float* xr = x + (size_t)row * DIM;
  float v0 = xr[tid], v1 = xr[tid + 256], v2 = xr[tid + 512];
  float s  = v0 + v1 + v2;
  float s2 = v0 * v0 + v1 * v1 + v2 * v2;
#pragma unroll
  for (int d = 1; d < 64; d <<= 1) { s += __shfl_xor(s, d); s2 += __shfl_xor(s2, d); }
  __shared__ float red[8];
  int wv = tid >> 6, ln = tid & 63;
  if (ln == 0) { red[wv] = s; red[wv + 4] = s2; }
  __syncthreads();
  s  = red[0] + red[1] + red[2] + red[3];
  s2 = red[4] + red[5] + red[6] + red[7];
  float mean = s * (1.0f / DIM);
  float var  = s2 * (1.0f / DIM) - mean * mean;
  float rs   = rsqrtf(var + LNEPS);
  bf16* outr = out + (size_t)row * DIM;
  outr[tid]       = (bf16)((v0 - mean) * rs * w[tid]       + b[tid]);
  outr[tid + 256] = (bf16)((v1 - mean) * rs * w[tid + 256] + b[tid + 256]);
  outr[tid + 512] = (bf16)((v2 - mean) * rs * w[tid + 512] + b[tid + 512]);
}

// ---------------- 128x128 BK=64 swizzled GEMM, XCD-chunked 1D grid ----------------
// chunk id -> (mt = chunk / Ntiles, nt = chunk % Ntiles): blocks sharing an A panel
// are consecutive within one XCD's contiguous chunk -> A fetched ~once device-wide.
// EPI 0: qkv scatter; 1: residual f32; 2: gelu bf16.
template <int EPI>
__global__ __launch_bounds__(256, 3)
void gemm128(const bf16* __restrict__ A, const bf16* __restrict__ Bw,
             int K, int Ncols, int Ntiles,
             const float* __restrict__ p0, const float* __restrict__ p1,
             void* __restrict__ outp) {
  __shared__ __align__(16) bf16 As[128 * 64];   // 16KB, rows of 128B (8x16B units)
  __shared__ __align__(16) bf16 Bs[128 * 64];   // 16KB
  const int tid  = threadIdx.x;
  const int wave = tid >> 6, lane = tid & 63;
  const int wm = wave >> 1, wn = wave & 1;       // 2x2 wave grid, 64x64 out per wave
  const int lr16 = lane & 15, hi16 = lane >> 4;

  // bijective XCD chunking (m204): round-robin dispatch -> contiguous tile chunk per XCD
  const int nwg = gridDim.x;
  const int q8 = nwg >> 3, r8 = nwg & 7;
  const int xcd = blockIdx.x & 7, jj8 = blockIdx.x >> 3;
  const int chunk = (xcd < r8 ? xcd * (q8 + 1) : r8 * (q8 + 1) + (xcd - r8) * q8) + jj8;
  const int mt = chunk / Ntiles, nt = chunk - mt * Ntiles;
  const int rowBase = mt * 128;
  const int colBase = nt * 128;
  const size_t Kb = (size_t)K * 2;
  const int KT = K >> 6;

  // swizzle: LDS[row][unit u] = G[row][u ^ (row&7)]; read unit g -> u = g ^ (row&7)
  const int s7 = lr16 & 7;
  const int colk0 = (hi16 ^ s7) * 16;          // kk=0 (k 0..31)
  const int colk1 = ((4 + hi16) ^ s7) * 16;    // kk=1 (k 32..63)
  const int rowb_a = (wm * 64 + lr16) * 128;   // + m*2048
  const int rowb_b = (wn * 64 + lr16) * 128;   // + n*2048

  // staging: round r covers rows r*32 + wave*8 + (lane>>3); lane unit = lane&7
  const int srow = wave * 8 + (lane >> 3);
  const int scb  = (((lane & 7) ^ ((lane >> 3) & 7)) * 16);
  const char* aSrcP[4];
  const char* bSrcP[4];
#pragma unroll
  for (int r = 0; r < 4; ++r) {
    int ra = rowBase + r * 32 + srow;
    if (ra > MROWS - 1) ra = MROWS - 1;        // clamp A rows (tail tile)
    aSrcP[r] = (const char*)A + (size_t)ra * Kb + scb;
    bSrcP[r] = (const char*)Bw + (size_t)(colBase + r * 32 + srow) * Kb + scb;
  }

  f32x4 acc[4][4] = {};

  for (int t = 0; t < KT; ++t) {
    const size_t koff = (size_t)t * 128;
#pragma unroll
    for (int r = 0; r < 4; ++r)
      gload_lds16(aSrcP[r] + koff, (char*)As + (r * 32 + wave * 8) * 128);
#pragma unroll
    for (int r = 0; r < 4; ++r)
      gload_lds16(bSrcP[r] + koff, (char*)Bs + (r * 32 + wave * 8) * 128);
    __syncthreads();   // drains vmcnt -> staged tile visible

    bf16x8 bfr[4][2];
#pragma unroll
    for (int n = 0; n < 4; ++n) {
      bfr[n][0] = *(const bf16x8*)((const char*)Bs + rowb_b + n * 2048 + colk0);
      bfr[n][1] = *(const bf16x8*)((const char*)Bs + rowb_b + n * 2048 + colk1);
    }
#pragma unroll
    for (int m = 0; m < 4; ++m) {
      bf16x8 a0 = *(const bf16x8*)((const char*)As + rowb_a + m * 2048 + colk0);
      bf16x8 a1 = *(const bf16x8*)((const char*)As + rowb_a + m * 2048 + colk1);
#pragma unroll
      for (int n = 0; n < 4; ++n) {
        acc[m][n] = __builtin_amdgcn_mfma_f32_16x16x32_bf16(a0, bfr[n][0], acc[m][n], 0, 0, 0);
        acc[m][n] = __builtin_amdgcn_mfma_f32_16x16x32_bf16(a1, bfr[n][1], acc[m][n], 0, 0, 0);
      }
    }
    __syncthreads();   // drains lgkmcnt -> all reads done before next stage
  }

  // ---- epilogue (C/D layout: col=lane&15, row=(lane>>4)*4+reg)
  const int rl = hi16 * 4;
  const int cl = lr16;
#pragma unroll
  for (int m = 0; m < 4; ++m) {
#pragma unroll
    for (int n = 0; n < 4; ++n) {
#pragma unroll
      for (int r = 0; r < 4; ++r) {
        int row = rowBase + wm * 64 + m * 16 + rl + r;
        int col = colBase + wn * 64 + n * 16 + cl;
        if (row >= MROWS) continue;
        float v = acc[m][n][r];
        if constexpr (EPI == 0) {
          int which = col / DIM;
          int jj = col - which * DIM;
          if (which == 0) v = (v + p0[jj]) * QSCALE;
          else if (which == 2) v = v + p1[jj];
          int bb = row / NTOK, nt2 = row - bb * NTOK;
          int h = jj >> 6, hd = jj & 63;
          ((bf16*)outp)[((size_t)(which * 768 + bb * HEADS + h) * NTOK + nt2) * 64 + hd] = (bf16)v;
        } else if constexpr (EPI == 1) {
          ((float*)outp)[(size_t)row * Ncols + col] =
              p1[(size_t)row * Ncols + col] + v + p0[col];
        } else {
          float t2 = v + p0[col];
          float g = 0.5f * t2 * (1.0f + erff(t2 * 0.70710678118654752f));
          ((bf16*)outp)[(size_t)row * Ncols + col] = (bf16)g;
        }
      }
    }
  }
}

// ---------------- fused attention v3: flash-style online softmax ----------------
#define VTS 232   /* Vt row stride (elements) */
__global__ __launch_bounds__(256, 4)
void attn_kernel(const bf16* __restrict__ qkv, const float* __restrict__ bias,
                 bf16* __restrict__ out) {
  const int bh = blockIdx.x;
  const int b = bh / HEADS, h = bh - b * HEADS;
  const bf16* qg = qkv + (size_t)bh * NTOK * HD;
  const bf16* kg = qg + (size_t)768 * NTOK * HD;
  const bf16* vg = qg + (size_t)1536 * NTOK * HD;

  __shared__ __align__(16) bf16 Vt[64 * VTS];       // 29.0KB
  __shared__ __align__(16) bf16 Ps[4][2][16 * 40];  // 10.0KB dbuf P chunks

  const int tid = threadIdx.x;
  for (int i = tid; i < NTOK * HD; i += 256) {
    int j = i >> 6, d = i & 63;
    Vt[d * VTS + j] = vg[i];
  }
  for (int i = tid; i < 64 * (VTS - NTOK); i += 256) {
    int d = i / (VTS - NTOK), j = NTOK + (i - d * (VTS - NTOK));
    Vt[d * VTS + j] = (bf16)0.0f;
  }
  __syncthreads();

  const int wave = tid >> 6, lane = tid & 63;
  const int lr = lane & 15, lg = lane >> 4;
  const int tstart = (wave == 0) ? 0 : 1 + wave * 3;   // 0,4,7,10
  const int tcount = (wave == 0) ? 4 : 3;
  const float* bh_bias = bias + (size_t)h * NTOK * NTOK;

  for (int ti = 0; ti < tcount; ++ti) {
    const int mi = tstart + ti;
    int qrow = mi * 16 + lr; if (qrow > NTOK - 1) qrow = NTOK - 1;
    bf16x8 aq0 = *(const bf16x8*)(qg + (size_t)qrow * 64 + lg * 8);
    bf16x8 aq1 = *(const bf16x8*)(qg + (size_t)qrow * 64 + 32 + lg * 8);

    f32x4 oacc[4] = {};
    float m[4] = {-1e30f, -1e30f, -1e30f, -1e30f};
    float l[4] = {0.f, 0.f, 0.f, 0.f};
    const int ivb = (mi * 16 + lg * 4 < NTOK) ? mi * 16 + lg * 4 : NTOK - 1;

#pragma unroll 1
    for (int kt = 0; kt < 7; ++kt) {
      const int j0 = kt * 32 + lr;
      const bf16* kp0 = kg + (size_t)(kt * 32 + lr) * 64 + lg * 8;
      const bf16* kp1 = kp0 + (size_t)16 * 64;
      f32x4 s0 = {}, s1 = {};
      s0 = __builtin_amdgcn_mfma_f32_16x16x32_bf16(aq0, *(const bf16x8*)kp0, s0, 0, 0, 0);
      s0 = __builtin_amdgcn_mfma_f32_16x16x32_bf16(aq1, *(const bf16x8*)(kp0 + 32), s0, 0, 0, 0);
      s1 = __builtin_amdgcn_mfma_f32_16x16x32_bf16(aq0, *(const bf16x8*)kp1, s1, 0, 0, 0);
      s1 = __builtin_amdgcn_mfma_f32_16x16x32_bf16(aq1, *(const bf16x8*)(kp1 + 32), s1, 0, 0, 0);

      bf16* buf = &Ps[wave][kt & 1][0];
#pragma unroll
      for (int r = 0; r < 4; ++r) {
        int iv = ivb + r; if (iv > NTOK - 1) iv = NTOK - 1;
        float sv0 = (j0 < NTOK)      ? s0[r] + bh_bias[(size_t)iv * NTOK + j0]      : -1e30f;
        float sv1 = (j0 + 16 < NTOK) ? s1[r] + bh_bias[(size_t)iv * NTOK + j0 + 16] : -1e30f;
        float cmax = fmaxf(sv0, sv1);
#pragma unroll
        for (int d = 1; d < 16; d <<= 1) cmax = fmaxf(cmax, __shfl_xor(cmax, d));
        float mnew = fmaxf(m[r], cmax);
        float scale = __expf(m[r] - mnew);
        m[r] = mnew;
        float e0 = __expf(sv0 - mnew);
        float e1 = __expf(sv1 - mnew);
        l[r] = l[r] * scale + e0 + e1;
#pragma unroll
        for (int nd = 0; nd < 4; ++nd) oacc[nd][r] *= scale;
        buf[(lg * 4 + r) * 40 + lr]      = (bf16)e0;
        buf[(lg * 4 + r) * 40 + 16 + lr] = (bf16)e1;
      }
      asm volatile("s_waitcnt lgkmcnt(0)" ::: "memory");
      __builtin_amdgcn_sched_barrier(0);
      bf16x8 pa = *(const bf16x8*)&buf[lr * 40 + lg * 8];
#pragma unroll
      for (int nd = 0; nd < 4; ++nd) {
        bf16x8 bv = *(const bf16x8*)&Vt[(nd * 16 + lr) * VTS + kt * 32 + lg * 8];
        oacc[nd] = __builtin_amdgcn_mfma_f32_16x16x32_bf16(pa, bv, oacc[nd], 0, 0, 0);
      }
    }

    float rowinv[4];
#pragma unroll
    for (int r = 0; r < 4; ++r) {
      float ls = l[r];
#pragma unroll
      for (int d = 1; d < 16; d <<= 1) ls += __shfl_xor(ls, d);
      rowinv[r] = 1.0f / ls;
    }

    bf16* Ob = &Ps[wave][0][0];
#pragma unroll
    for (int nd = 0; nd < 4; ++nd)
#pragma unroll
      for (int r = 0; r < 4; ++r)
        Ob[(lg * 4 + r) * 72 + nd * 16 + lr] = (bf16)(oacc[nd][r] * rowinv[r]);
    asm volatile("s_waitcnt lgkmcnt(0)" ::: "memory");
    __builtin_amdgcn_sched_barrier(0);
    const int rows = NTOK - mi * 16;
#pragma unroll
    for (int pass = 0; pass < 2; ++pass) {
      int orow = pass * 8 + (lane >> 3);
      if (orow < rows) {
        bf16x8 v = *(const bf16x8*)&Ob[orow * 72 + (lane & 7) * 8];
        *(bf16x8*)(out + (size_t)(b * NTOK + mi * 16 + orow) * DIM + h * 64 + (lane & 7) * 8) = v;
      }
    }
  }
}

// ---------------- launch ----------------
extern "C" void kernel_launch(void* const* d_in, const int* in_sizes, int n_in,
                              void* d_out, int out_size, void* d_ws, size_t ws_size,
                              hipStream_t stream) {
  const float* x    = (const float*)d_in[0];
  const float* n1w  = (const float*)d_in[1];
  const float* n1b  = (const float*)d_in[2];
  const float* qkvw = (const float*)d_in[3];
  const float* qb   = (const float*)d_in[4];
  const float* vb   = (const float*)d_in[5];
  const float* pw   = (const float*)d_in[6];
  const float* pb   = (const float*)d_in[7];
  const float* rh   = (const float*)d_in[8];
  const float* rw   = (const float*)d_in[9];
  const float* n2w  = (const float*)d_in[10];
  const float* n2b  = (const float*)d_in[11];
  const float* f1w  = (const float*)d_in[12];
  const float* f1b  = (const float*)d_in[13];
  const float* f2w  = (const float*)d_in[14];
  const float* f2b  = (const float*)d_in[15];
  const int* hidx   = (const int*)d_in[16];
  const int* widx   = (const int*)d_in[17];

  char* ws = (char*)d_ws;
  size_t off = 0;
  auto alloc = [&](size_t bytes) {
    void* p = ws + off;
    off += (bytes + 255) & ~(size_t)255;
    return p;
  };
  bf16* wqkv  = (bf16*)alloc((size_t)2304 * 768 * 2);
  bf16* wproj = (bf16*)alloc((size_t)768 * 768 * 2);
  bf16* wfc1  = (bf16*)alloc((size_t)3072 * 768 * 2);
  bf16* wfc2  = (bf16*)alloc((size_t)768 * 3072 * 2);
  float* biasT = (float*)alloc((size_t)HEADS * NTOK * NTOK * 4);
  bf16* hbf = (bf16*)alloc((size_t)MROWS * 768 * 2);
  float* x1 = (float*)alloc((size_t)MROWS * 768 * 4);
  char* region = (char*)alloc((size_t)MPAD * HIDN * 2);
  bf16* qkv   = (bf16*)region;                                       // 58.1 MB
  bf16* attno = (bf16*)(region + (size_t)2304 * NTOK * 64 * 2);      // 19.4 MB
  bf16* mbuf  = (bf16*)region;                                       // FC1 out overlays qkv+attno

  conv_kernel<<<(2304 * 768 / 4 + 255) / 256, 256, 0, stream>>>(qkvw, wqkv, 2304 * 768 / 4);
  conv_kernel<<<(768 * 768 / 4 + 255) / 256, 256, 0, stream>>>(pw, wproj, 768 * 768 / 4);
  conv_kernel<<<(3072 * 768 / 4 + 255) / 256, 256, 0, stream>>>(f1w, wfc1, 3072 * 768 / 4);
  conv_kernel<<<(768 * 3072 / 4 + 255) / 256, 256, 0, stream>>>(f2w, wfc2, 768 * 3072 / 4);
  bias_kernel<<<(HEADS * NTOK * NTOK + 255) / 256, 256, 0, stream>>>(rh, rw, hidx, widx, biasT);

  const int MT = MPAD / 128;  // 99
  ln_kernel<<<MROWS, 256, 0, stream>>>(x, n1w, n1b, hbf);
  gemm128<0><<<MT * 18, 256, 0, stream>>>(hbf, wqkv, 768, 2304, 18, qb, vb, qkv);
  attn_kernel<<<768, 256, 0, stream>>>(qkv, biasT, attno);
  gemm128<1><<<MT * 6, 256, 0, stream>>>(attno, wproj, 768, 768, 6, pb, x, x1);
  ln_kernel<<<MROWS, 256, 0, stream>>>(x1, n2w, n2b, hbf);
  gemm128<2><<<MT * 24, 256, 0, stream>>>(hbf, wfc1, 768, HIDN, 24, f1b, nullptr, mbuf);
  gemm128<1><<<MT * 6, 256, 0, stream>>>(mbuf, wfc2, HIDN, 768, 6, f2b, x1, d_out);
}